// Round 2
// baseline (139.216 us; speedup 1.0000x reference)
//
#include <hip/hip_runtime.h>
#include <math.h>

#define BB 64
#define QQ 900
#define NN 30
#define C1 1001
#define NUMC 1000
#define QN (QQ * NN)            // 27000
#define NO_OBJ_W 0.1f

#define MT 960                  // match kernel block size (15 waves), >= QQ

// ---- persistent device scratch (fully rewritten every call) ----
__device__ __align__(16) float g_C[BB * QN];   // cost matrices [b][q][t]
__device__ float  g_logZ[BB * QQ];             // per-query logsumexp
__device__ float  g_noobj[BB * QQ];            // per-query no-object nll = logZ - row[1000]
__device__ float4 g_xyxy[BB * QQ];             // clipped pred boxes (xyxy)
__device__ int    g_pi[BB * NN];               // matched query idx
__device__ int    g_ti[BB * NN];               // matched target idx

__device__ __forceinline__ float giou_f(float ax1, float ay1, float ax2, float ay2,
                                        float bx1, float by1, float bx2, float by2) {
    float ix1 = fmaxf(ax1, bx1), iy1 = fmaxf(ay1, by1);
    float ix2 = fminf(ax2, bx2), iy2 = fminf(ay2, by2);
    float iw = fmaxf(ix2 - ix1, 0.f), ih = fmaxf(iy2 - iy1, 0.f);
    float inter = iw * ih;
    float areaA = fmaxf(ax2 - ax1, 0.f) * fmaxf(ay2 - ay1, 0.f);
    float areaB = fmaxf(bx2 - bx1, 0.f) * fmaxf(by2 - by1, 0.f);
    float uni = areaA + areaB - inter;
    float iou = inter / fmaxf(uni, 1e-6f);
    float cx1 = fminf(ax1, bx1), cy1 = fminf(ay1, by1);
    float cx2 = fmaxf(ax2, bx2), cy2 = fmaxf(ay2, by2);
    float cw = fmaxf(cx2 - cx1, 0.f), ch = fmaxf(cy2 - cy1, 0.f);
    float ac = cw * ch;
    return iou - (ac - uni) / fmaxf(ac, 1e-6f);
}

// ---- K1: per-query softmax + cost matrix + noobj nll ----
__global__ __launch_bounds__(256) void cost_kernel(const float* __restrict__ logits,
                                                   const float* __restrict__ pboxes,
                                                   const int*   __restrict__ labels,
                                                   const float* __restrict__ tboxes) {
    int gwave = (blockIdx.x * blockDim.x + threadIdx.x) >> 6;  // global query idx
    int lane = threadIdx.x & 63;
    if (gwave >= BB * QQ) return;
    int b = gwave / QQ;

    const float* row = logits + (size_t)gwave * C1;
    float v[16];
#pragma unroll
    for (int i = 0; i < 16; ++i) {
        int idx = lane + i * 64;
        v[i] = (idx < C1) ? row[idx] : -INFINITY;
    }
    float mx = v[0];
#pragma unroll
    for (int i = 1; i < 16; ++i) mx = fmaxf(mx, v[i]);
#pragma unroll
    for (int off = 32; off; off >>= 1) mx = fmaxf(mx, __shfl_xor(mx, off));
    float s = 0.f;
#pragma unroll
    for (int i = 0; i < 16; ++i) {
        int idx = lane + i * 64;
        if (idx < C1) s += expf(v[i] - mx);
    }
#pragma unroll
    for (int off = 32; off; off >>= 1) s += __shfl_xor(s, off);
    float logZ = mx + logf(s);

    // row[1000] lives at lane 40, i=15 (40 + 15*64 == 1000)
    float row1000 = __shfl(v[15], 40);

    // pred box -> clipped xyxy (uniform across wave)
    const float* pb = pboxes + (size_t)gwave * 4;
    float cx = pb[0], cy = pb[1], w = pb[2], h = pb[3];
    float x1 = fminf(fmaxf(cx - 0.5f * w, 0.f), 1.f);
    float y1 = fminf(fmaxf(cy - 0.5f * h, 0.f), 1.f);
    float x2 = fminf(fmaxf(cx + 0.5f * w, 0.f), 1.f);
    float y2 = fminf(fmaxf(cy + 0.5f * h, 0.f), 1.f);

    if (lane == 0) {
        g_logZ[gwave] = logZ;
        g_noobj[gwave] = logZ - row1000;
        g_xyxy[gwave] = make_float4(x1, y1, x2, y2);
    }

    if (lane < NN) {
        int t = lane;
        int lab = labels[b * NN + t];
        float pcls = expf(row[lab] - logZ);
        const float* tb = tboxes + ((size_t)(b * NN + t)) * 4;
        float tx1 = tb[0], ty1 = tb[1], tx2 = tb[2], ty2 = tb[3];
        float l1 = fabsf(x1 - tx1) + fabsf(y1 - ty1) + fabsf(x2 - tx2) + fabsf(y2 - ty2);
        float g = giou_f(x1, y1, x2, y2, tx1, ty1, tx2, ty2);
        g_C[(size_t)gwave * NN + t] = -pcls + 5.0f * l1 - 2.0f * g;
    }
}

// ---- K2: greedy matcher, one block per batch, one row per thread ----
__global__ __launch_bounds__(MT) void match_kernel() {
    int b = blockIdx.x;
    int tid = threadIdx.x;
    int lane = tid & 63, wid = tid >> 6;
    bool alive = tid < QQ;

    unsigned ord[NN];
    if (alive) {
        const float2* r2 = (const float2*)(g_C + (size_t)b * QN + tid * NN);
#pragma unroll
        for (int k = 0; k < NN / 2; ++k) {
            float2 v = r2[k];
            unsigned ux = __float_as_uint(v.x);
            unsigned uy = __float_as_uint(v.y);
            ord[2 * k]     = (ux & 0x80000000u) ? ~ux : (ux | 0x80000000u);
            ord[2 * k + 1] = (uy & 0x80000000u) ? ~uy : (uy | 0x80000000u);
        }
    } else {
#pragma unroll
        for (int t = 0; t < NN; ++t) ord[t] = 0xFFFFFFFFu;
    }
    // row argmin (value, then smallest t — matches flat-index tie-break)
    unsigned bo = ord[0];
    int bt = 0;
#pragma unroll
    for (int t = 1; t < NN; ++t) if (ord[t] < bo) { bo = ord[t]; bt = t; }

    __shared__ unsigned long long s_red[MT / 64];

    for (int it = 0; it < NN; ++it) {
        unsigned long long key = alive
            ? (((unsigned long long)bo << 32) | (unsigned)(tid * NN + bt))
            : 0xFFFFFFFFFFFFFFFFull;
#pragma unroll
        for (int off = 32; off; off >>= 1) {
            unsigned long long o = __shfl_xor(key, off);
            key = (o < key) ? o : key;
        }
        if (lane == 0) s_red[wid] = key;
        __syncthreads();
        // every wave redundantly computes the block min (no serial thread-0 stage)
        unsigned long long best = s_red[0];
#pragma unroll
        for (int w = 1; w < MT / 64; ++w) best = (s_red[w] < best) ? s_red[w] : best;
        int e = (int)(unsigned)best;
        int pq = e / NN;
        int pt = e - pq * NN;
        if (tid == 0) { g_pi[b * NN + it] = pq; g_ti[b * NN + it] = pt; }
        __syncthreads();   // all s_red reads done before next iteration's writes

        if (alive) {
            if (tid == pq) {
                alive = false;
            } else {
#pragma unroll
                for (int t = 0; t < NN; ++t) if (t == pt) ord[t] = 0xFFFFFFFFu;
                if (bt == pt) {   // own argmin died -> rescan
                    bo = ord[0]; bt = 0;
#pragma unroll
                    for (int t = 1; t < NN; ++t) if (ord[t] < bo) { bo = ord[t]; bt = t; }
                }
            }
        }
    }
}

// ---- K3: fused losses + final reduce (single block) ----
__global__ __launch_bounds__(1024) void loss_kernel(const float* __restrict__ logits,
                                                    const int*   __restrict__ labels,
                                                    const float* __restrict__ tboxes,
                                                    float* __restrict__ out) {
    int tid = threadIdx.x;

    // part A: global sum of no-object nll over all (b,q)
    float sA = 0.f;
    for (int i = tid; i < BB * QQ; i += 1024) sA += g_noobj[i];

    // part B: matched corrections + box losses (1920 pairs)
    float sB = 0.f, sL = 0.f, sG = 0.f;
    for (int i = tid; i < BB * NN; i += 1024) {
        int b = i / NN;
        int pq = g_pi[i], pt = g_ti[i];
        int gq = b * QQ + pq;
        int lab = labels[b * NN + pt];
        float mnll = g_logZ[gq] - logits[(size_t)gq * C1 + lab];
        sB += mnll - NO_OBJ_W * g_noobj[gq];
        float4 p = g_xyxy[gq];
        const float* tb = tboxes + ((size_t)(b * NN + pt)) * 4;
        float tx1 = tb[0], ty1 = tb[1], tx2 = tb[2], ty2 = tb[3];
        sL += fabsf(p.x - tx1) + fabsf(p.y - ty1) + fabsf(p.z - tx2) + fabsf(p.w - ty2);
        sG += 1.0f - giou_f(p.x, p.y, p.z, p.w, tx1, ty1, tx2, ty2);
    }

    __shared__ float s4[16][4];
    int lane = tid & 63, wid = tid >> 6;
    float vv[4] = {sA, sB, sL, sG};
#pragma unroll
    for (int j = 0; j < 4; ++j) {
        float x = vv[j];
#pragma unroll
        for (int off = 32; off; off >>= 1) x += __shfl_xor(x, off);
        if (lane == 0) s4[wid][j] = x;
    }
    __syncthreads();
    if (tid == 0) {
        float a = 0.f, bs = 0.f, l = 0.f, g = 0.f;
        for (int w = 0; w < 16; ++w) {
            a += s4[w][0]; bs += s4[w][1]; l += s4[w][2]; g += s4[w][3];
        }
        // per-batch CE denominator is exactly 30*1 + 870*0.1 = 117
        float ce = (NO_OBJ_W * a + bs) / (float)(BB * 117);
        float l1 = l / (float)(BB * NN * 4);
        float gl = g / (float)(BB * NN);
        out[0] = ce + 5.0f * l1 + 2.0f * gl;
        out[1] = ce;
        out[2] = l1;
        out[3] = gl;
    }
}

extern "C" void kernel_launch(void* const* d_in, const int* in_sizes, int n_in,
                              void* d_out, int out_size, void* d_ws, size_t ws_size,
                              hipStream_t stream) {
    const float* pred_logits = (const float*)d_in[0];
    const float* pred_boxes  = (const float*)d_in[1];
    const int*   tgt_labels  = (const int*)d_in[2];
    const float* tgt_boxes   = (const float*)d_in[3];
    float* out = (float*)d_out;

    int nwaves = BB * QQ;                       // one wave per query
    cost_kernel<<<nwaves / 4, 256, 0, stream>>>(pred_logits, pred_boxes, tgt_labels, tgt_boxes);
    match_kernel<<<BB, MT, 0, stream>>>();
    loss_kernel<<<1, 1024, 0, stream>>>(pred_logits, tgt_labels, tgt_boxes, out);
}

// Round 3
// 119.233 us; speedup vs baseline: 1.1676x; 1.1676x over previous
//
#include <hip/hip_runtime.h>
#include <math.h>

#define BB 64
#define QQ 900
#define NN 30
#define C1 1001
#define NUMC 1000
#define QN (QQ * NN)            // 27000
#define NO_OBJ_W 0.1f

#define MT 960                  // match kernel block size (15 waves), >= QQ

// ---- persistent device scratch (fully rewritten every call) ----
__device__ __align__(16) float g_C[BB * QN];   // cost matrices [b][q][t]
__device__ float  g_logZ[BB * QQ];             // per-query logsumexp
__device__ float  g_noobj[BB * QQ];            // per-query no-object nll
__device__ float4 g_xyxy[BB * QQ];             // clipped pred boxes (xyxy)
__device__ int    g_pi[BB * NN];               // matched query idx
__device__ int    g_ti[BB * NN];               // matched target idx
__device__ float4 g_partial[BB];               // per-batch (ce_num, l1, gl, _)

__device__ __forceinline__ float giou_f(float ax1, float ay1, float ax2, float ay2,
                                        float bx1, float by1, float bx2, float by2) {
    float ix1 = fmaxf(ax1, bx1), iy1 = fmaxf(ay1, by1);
    float ix2 = fminf(ax2, bx2), iy2 = fminf(ay2, by2);
    float iw = fmaxf(ix2 - ix1, 0.f), ih = fmaxf(iy2 - iy1, 0.f);
    float inter = iw * ih;
    float areaA = fmaxf(ax2 - ax1, 0.f) * fmaxf(ay2 - ay1, 0.f);
    float areaB = fmaxf(bx2 - bx1, 0.f) * fmaxf(by2 - by1, 0.f);
    float uni = areaA + areaB - inter;
    float iou = inter / fmaxf(uni, 1e-6f);
    float cx1 = fminf(ax1, bx1), cy1 = fminf(ay1, by1);
    float cx2 = fmaxf(ax2, bx2), cy2 = fmaxf(ay2, by2);
    float cw = fmaxf(cx2 - cx1, 0.f), ch = fmaxf(cy2 - cy1, 0.f);
    float ac = cw * ch;
    return iou - (ac - uni) / fmaxf(ac, 1e-6f);
}

// ---- K1: per-query softmax + cost matrix + noobj nll ----
// one wave per query; 16B-aligned float4 interior + scalar head/tail
__global__ __launch_bounds__(256) void cost_kernel(const float* __restrict__ logits,
                                                   const float* __restrict__ pboxes,
                                                   const int*   __restrict__ labels,
                                                   const float* __restrict__ tboxes) {
    int gwave = (blockIdx.x * blockDim.x + threadIdx.x) >> 6;  // global query idx
    int lane = threadIdx.x & 63;
    if (gwave >= BB * QQ) return;
    int b = gwave / QQ;

    size_t s = (size_t)gwave * C1;     // first element of this row
    size_t a0 = (s + 3) >> 2;          // first fully-inside aligned quad
    size_t a1 = (s + C1) >> 2;         // one past last fully-inside quad
    int nq = (int)(a1 - a0);           // 249..250 interior quads
    int hh = (int)(a0 * 4 - s);        // 0..3 head elements
    int tt = (int)((s + C1) - a1 * 4); // 0..3 tail elements
    const float4* L4 = (const float4*)logits;

    float4 v4[4];
#pragma unroll
    for (int i = 0; i < 4; ++i) {
        int q = lane + 64 * i;
        v4[i] = (q < nq) ? L4[a0 + q]
                         : make_float4(-INFINITY, -INFINITY, -INFINITY, -INFINITY);
    }
    float e1 = (lane < hh) ? logits[s + lane] : -INFINITY;
    float e2 = (lane < tt) ? logits[a1 * 4 + lane] : -INFINITY;

    float mx = fmaxf(e1, e2);
#pragma unroll
    for (int i = 0; i < 4; ++i)
        mx = fmaxf(mx, fmaxf(fmaxf(v4[i].x, v4[i].y), fmaxf(v4[i].z, v4[i].w)));
#pragma unroll
    for (int off = 32; off; off >>= 1) mx = fmaxf(mx, __shfl_xor(mx, off));

    float sm = __expf(e1 - mx) + __expf(e2 - mx);
#pragma unroll
    for (int i = 0; i < 4; ++i) {
        sm += __expf(v4[i].x - mx);
        sm += __expf(v4[i].y - mx);
        sm += __expf(v4[i].z - mx);
        sm += __expf(v4[i].w - mx);
    }
#pragma unroll
    for (int off = 32; off; off >>= 1) sm += __shfl_xor(sm, off);
    float logZ = mx + __logf(sm);

    float row1000 = logits[s + 1000];   // wave-uniform broadcast load (L1 hit)

    // pred box -> clipped xyxy (uniform across wave)
    const float* pb = pboxes + (size_t)gwave * 4;
    float cx = pb[0], cy = pb[1], w = pb[2], h = pb[3];
    float x1 = fminf(fmaxf(cx - 0.5f * w, 0.f), 1.f);
    float y1 = fminf(fmaxf(cy - 0.5f * h, 0.f), 1.f);
    float x2 = fminf(fmaxf(cx + 0.5f * w, 0.f), 1.f);
    float y2 = fminf(fmaxf(cy + 0.5f * h, 0.f), 1.f);

    if (lane == 0) {
        g_logZ[gwave] = logZ;
        g_noobj[gwave] = logZ - row1000;
        g_xyxy[gwave] = make_float4(x1, y1, x2, y2);
    }

    if (lane < NN) {
        int t = lane;
        int lab = labels[b * NN + t];
        float pcls = __expf(logits[s + lab] - logZ);   // row line is L1-resident
        const float* tb = tboxes + ((size_t)(b * NN + t)) * 4;
        float tx1 = tb[0], ty1 = tb[1], tx2 = tb[2], ty2 = tb[3];
        float l1 = fabsf(x1 - tx1) + fabsf(y1 - ty1) + fabsf(x2 - tx2) + fabsf(y2 - ty2);
        float g = giou_f(x1, y1, x2, y2, tx1, ty1, tx2, ty2);
        g_C[(size_t)gwave * NN + t] = -pcls + 5.0f * l1 - 2.0f * g;
    }
}

// ---- K2: greedy matcher, one block per batch, one row per thread ----
// single barrier per iteration via double-buffered reduce slots
__global__ __launch_bounds__(MT) void match_kernel() {
    int b = blockIdx.x;
    int tid = threadIdx.x;
    int lane = tid & 63, wid = tid >> 6;
    bool alive = tid < QQ;

    unsigned ord[NN];
    if (alive) {
        const float2* r2 = (const float2*)(g_C + (size_t)b * QN + tid * NN);
#pragma unroll
        for (int k = 0; k < NN / 2; ++k) {
            float2 v = r2[k];
            unsigned ux = __float_as_uint(v.x);
            unsigned uy = __float_as_uint(v.y);
            ord[2 * k]     = (ux & 0x80000000u) ? ~ux : (ux | 0x80000000u);
            ord[2 * k + 1] = (uy & 0x80000000u) ? ~uy : (uy | 0x80000000u);
        }
    } else {
#pragma unroll
        for (int t = 0; t < NN; ++t) ord[t] = 0xFFFFFFFFu;
    }
    unsigned bo = ord[0];
    int bt = 0;
#pragma unroll
    for (int t = 1; t < NN; ++t) if (ord[t] < bo) { bo = ord[t]; bt = t; }

    __shared__ unsigned long long s_red[2][MT / 64];

    for (int it = 0; it < NN; ++it) {
        unsigned long long key = alive
            ? (((unsigned long long)bo << 32) | (unsigned)(tid * NN + bt))
            : 0xFFFFFFFFFFFFFFFFull;
#pragma unroll
        for (int off = 32; off; off >>= 1) {
            unsigned long long o = __shfl_xor(key, off);
            key = (o < key) ? o : key;
        }
        int buf = it & 1;
        if (lane == 0) s_red[buf][wid] = key;
        __syncthreads();
        unsigned long long best = s_red[buf][0];
#pragma unroll
        for (int w = 1; w < MT / 64; ++w) best = (s_red[buf][w] < best) ? s_red[buf][w] : best;
        int e = (int)(unsigned)best;
        int pq = e / NN;
        int pt = e - pq * NN;
        if (tid == 0) { g_pi[b * NN + it] = pq; g_ti[b * NN + it] = pt; }
        // next iteration writes the other buffer; its barrier orders reuse of this one

        if (alive) {
            if (tid == pq) {
                alive = false;
            } else {
#pragma unroll
                for (int t = 0; t < NN; ++t) if (t == pt) ord[t] = 0xFFFFFFFFu;
                if (bt == pt) {
                    bo = ord[0]; bt = 0;
#pragma unroll
                    for (int t = 1; t < NN; ++t) if (ord[t] < bo) { bo = ord[t]; bt = t; }
                }
            }
        }
    }
}

// ---- K3: per-batch losses (CE algebra: denom == 117 exactly) ----
__global__ __launch_bounds__(256) void loss_kernel(const float* __restrict__ logits,
                                                   const int*   __restrict__ labels,
                                                   const float* __restrict__ tboxes) {
    int b = blockIdx.x;
    int tid = threadIdx.x;

    float sA = 0.f;                                   // sum of noobj nll over batch
    for (int q = tid; q < QQ; q += 256) sA += g_noobj[b * QQ + q];

    float sB = 0.f, sL = 0.f, sG = 0.f;               // matched corrections + box losses
    if (tid < NN) {
        int pq = g_pi[b * NN + tid], pt = g_ti[b * NN + tid];
        int gq = b * QQ + pq;
        int lab = labels[b * NN + pt];
        float mnll = g_logZ[gq] - logits[(size_t)gq * C1 + lab];
        sB = mnll - NO_OBJ_W * g_noobj[gq];
        float4 p = g_xyxy[gq];
        const float* tb = tboxes + ((size_t)(b * NN + pt)) * 4;
        float tx1 = tb[0], ty1 = tb[1], tx2 = tb[2], ty2 = tb[3];
        sL = fabsf(p.x - tx1) + fabsf(p.y - ty1) + fabsf(p.z - tx2) + fabsf(p.w - ty2);
        sG = 1.0f - giou_f(p.x, p.y, p.z, p.w, tx1, ty1, tx2, ty2);
    }

    __shared__ float s4[4][4];
    int lane = tid & 63, wid = tid >> 6;
    float vv[4] = {sA, sB, sL, sG};
#pragma unroll
    for (int j = 0; j < 4; ++j) {
        float x = vv[j];
#pragma unroll
        for (int off = 32; off; off >>= 1) x += __shfl_xor(x, off);
        if (lane == 0) s4[wid][j] = x;
    }
    __syncthreads();
    if (tid == 0) {
        float a = 0.f, bs = 0.f, l = 0.f, g = 0.f;
        for (int w = 0; w < 4; ++w) { a += s4[w][0]; bs += s4[w][1]; l += s4[w][2]; g += s4[w][3]; }
        g_partial[b] = make_float4(NO_OBJ_W * a + bs, l, g, 0.f);
    }
}

// ---- K4: reduce over batches ----
__global__ __launch_bounds__(64) void final_kernel(float* __restrict__ out) {
    int b = threadIdx.x;  // 64 == BB
    float4 p = g_partial[b];
    float ce = p.x, l1 = p.y, gl = p.z;
#pragma unroll
    for (int off = 32; off; off >>= 1) {
        ce += __shfl_xor(ce, off);
        l1 += __shfl_xor(l1, off);
        gl += __shfl_xor(gl, off);
    }
    if (b == 0) {
        ce /= (float)(BB * 117);          // per-batch CE denom is exactly 117
        l1 /= (float)(BB * NN * 4);
        gl /= (float)(BB * NN);
        out[0] = ce + 5.0f * l1 + 2.0f * gl;
        out[1] = ce;
        out[2] = l1;
        out[3] = gl;
    }
}

extern "C" void kernel_launch(void* const* d_in, const int* in_sizes, int n_in,
                              void* d_out, int out_size, void* d_ws, size_t ws_size,
                              hipStream_t stream) {
    const float* pred_logits = (const float*)d_in[0];
    const float* pred_boxes  = (const float*)d_in[1];
    const int*   tgt_labels  = (const int*)d_in[2];
    const float* tgt_boxes   = (const float*)d_in[3];
    float* out = (float*)d_out;

    int nwaves = BB * QQ;                       // one wave per query
    cost_kernel<<<nwaves / 4, 256, 0, stream>>>(pred_logits, pred_boxes, tgt_labels, tgt_boxes);
    match_kernel<<<BB, MT, 0, stream>>>();
    loss_kernel<<<BB, 256, 0, stream>>>(pred_logits, tgt_labels, tgt_boxes);
    final_kernel<<<1, 64, 0, stream>>>(out);
}